// Round 11
// baseline (272.363 us; speedup 1.0000x reference)
//
#include <hip/hip_runtime.h>
#include <math.h>

// GCN: 2-kernel atomic-free CSR build (per-block bin-sorted arena -> fixed-region bucket sort),
// bf16-MFMA GEMM, fused gather+LN+ReLU agg, per-graph pool. 9 dispatches.
// N=50000, E=800000, D=128, G=64. Requires N,src,dst < 65536, EB <= 512.

#define NDIM 128
#define LN_EPS 1e-5f
#define NGRAPH 64
#define EPB 2048
#define CSR_CAP 8192          // per-bucket csr region (mean 4096, +64 sigma)

typedef __attribute__((ext_vector_type(8))) short short8;
typedef __attribute__((ext_vector_type(8))) ushort ushort8;
typedef __attribute__((ext_vector_type(4))) float f32x4;

__device__ __forceinline__ ushort f2bf(float f) {
    unsigned u = __float_as_uint(f);
    return (ushort)((u + 0x7FFF + ((u >> 16) & 1)) >> 16);
}
__device__ __forceinline__ float bf2f(ushort b) {
    return __uint_as_float(((unsigned)b) << 16);
}

__device__ __forceinline__ uint block_excl_scan(uint v, uint* s) {
    int t = threadIdx.x;
    s[t] = v; __syncthreads();
    #pragma unroll
    for (int off = 1; off < 256; off <<= 1) {
        uint x = (t >= off) ? s[t - off] : 0u;
        __syncthreads();
        s[t] += x;
        __syncthreads();
    }
    uint incl = s[t];
    __syncthreads();
    return incl - v;
}

// ---------------- build pass 1: per-block bin-sorted arena ----------------
// arena[b*EPB + r]: block b's edges, sorted by bin (dst>>8); hist[b*257+j] = scanned
// within-block bin offset (exclusive); hist[b*257+256] = block edge count.

__global__ __launch_bounds__(256) void k_build1(const int* __restrict__ src, const int* __restrict__ dst,
                                                uint* __restrict__ hist, uint* __restrict__ arena, int E) {
    __shared__ uint h[256], s[256], rank[256];
    int t = threadIdx.x, b = blockIdx.x;
    h[t] = 0; __syncthreads();
    int e0 = b * EPB;
    #pragma unroll
    for (int i = 0; i < 8; i++) {
        int e = e0 + i * 256 + t;
        if (e < E) atomicAdd(&h[((uint)dst[e]) >> 8], 1u);
    }
    __syncthreads();
    uint cnt = h[t];
    uint off = block_excl_scan(cnt, s);
    hist[(size_t)b * 257 + t] = off;
    if (t == 0) hist[(size_t)b * 257 + 256] = (uint)(min(E - e0, EPB));
    rank[t] = off;
    __syncthreads();
    #pragma unroll
    for (int i = 0; i < 8; i++) {
        int e = e0 + i * 256 + t;
        if (e < E) {
            uint d = (uint)dst[e], sv = (uint)src[e];
            uint bin = d >> 8;
            uint r = atomicAdd(&rank[bin], 1u);
            arena[(size_t)b * EPB + r] = (d << 16) | sv;
        }
    }
}

// ---------------- build pass 2: per-bucket sort into fixed csr regions ----------------
// bucket b: gathers chunks (arena[r*EPB + hist[r][b] .. ]) from all blocks, LDS-histograms
// by dst&255, scans (pad4), places. bd[n] = (base, deg). Riders (b>=NB) convert weights.

__global__ __launch_bounds__(256) void k_sort2b(const uint* __restrict__ arena, const uint* __restrict__ hist,
                                                const int* __restrict__ batch,
                                                ushort* __restrict__ csr, int2* __restrict__ bd,
                                                float* __restrict__ dinv,
                                                int* __restrict__ gstart, int* __restrict__ gend,
                                                const float* __restrict__ Ws, ushort* __restrict__ Wt,
                                                int N, int NB, int EB) {
    __shared__ uint h[256], nbase[256], s[256];
    __shared__ uint coff[512], csz[512];
    int t = threadIdx.x, b = blockIdx.x;
    if (b >= NB) {      // weight-prep rider blocks
        int l = b - NB;
        const float* wsrc = Ws + (size_t)l * NDIM * NDIM;
        char* o = (char*)(Wt + (size_t)l * NDIM * NDIM);
        for (int idx = t; idx < NDIM * NDIM; idx += 256) {
            int k = idx >> 7, nn = idx & 127;
            int byte = ((nn * NDIM + k) * 2) ^ ((nn & 7) << 4);
            *(ushort*)(o + byte) = f2bf(wsrc[idx]);
        }
        return;
    }
    // chunk descriptors for this bucket
    for (int r = t; r < EB; r += 256) {
        uint o  = hist[(size_t)r * 257 + b];
        uint nx = (b < 255) ? hist[(size_t)r * 257 + b + 1] : hist[(size_t)r * 257 + 256];
        coff[r] = r * EPB + o;
        csz[r]  = nx - o;
    }
    h[t] = 0; __syncthreads();
    // pass 1: histogram by node-in-bucket
    for (int r = t; r < EB; r += 256) {
        uint c0 = coff[r], cn = csz[r];
        for (uint j = 0; j < cn; j++)
            atomicAdd(&h[(arena[c0 + j] >> 16) & 255u], 1u);
    }
    __syncthreads();
    uint dg = h[t];
    uint excl = block_excl_scan((dg + 3u) & ~3u, s);
    uint myb = (uint)b * CSR_CAP + excl;
    nbase[t] = myb;
    int n = b * 256 + t;
    if (n < N) {
        bd[n] = make_int2((int)myb, (int)dg);
        dinv[n] = rsqrtf((float)(dg + 1u));
        int g = batch[n];
        if (n == 0 || batch[n - 1] != g) gstart[g] = n;
        if (n == N - 1 || batch[n + 1] != g) gend[g] = n + 1;
    }
    h[t] = 0; __syncthreads();
    // pass 2: place
    for (int r = t; r < EB; r += 256) {
        uint c0 = coff[r], cn = csz[r];
        for (uint j = 0; j < cn; j++) {
            uint e = arena[c0 + j];
            uint bin = (e >> 16) & 255u;
            uint rk = atomicAdd(&h[bin], 1u);
            csr[nbase[bin] + rk] = (ushort)(e & 0xFFFFu);
        }
    }
}

// ---------------- GEMM: C[N,128] = (A @ W) * dinv[row], bf16 MFMA ----------------

template <bool AF32>
__global__ __launch_bounds__(256) void k_gemm(const void* __restrict__ Ap, const ushort* __restrict__ Wt,
                                              ushort* __restrict__ C, const float* __restrict__ dinv, int N) {
    __shared__ char sW[32768];
    __shared__ ushort sC[64 * NDIM];
    int tid = threadIdx.x;
    {
        const float4* g = (const float4*)Wt;
        float4* s = (float4*)sW;
        #pragma unroll
        for (int i = 0; i < 8; i++) s[tid + 256 * i] = g[tid + 256 * i];
    }
    __syncthreads();

    int wave = tid >> 6, lane = tid & 63;
    int l15 = lane & 15, lhi = lane >> 4;
    int rw = blockIdx.x * 64 + wave * 16;

    f32x4 acc[8];
    #pragma unroll
    for (int n = 0; n < 8; n++) acc[n] = f32x4{0.f, 0.f, 0.f, 0.f};

    const float*  Af = (const float*)Ap;
    const ushort* Ab = (const ushort*)Ap;

    #pragma unroll
    for (int ks = 0; ks < 4; ks++) {
        int k = ks * 32 + lhi * 8;
        short8 a = short8{};
        int r = rw + l15;
        if (r < N) {
            if (AF32) {
                float4 v0 = *(const float4*)&Af[(size_t)r * NDIM + k];
                float4 v1 = *(const float4*)&Af[(size_t)r * NDIM + k + 4];
                short8 t;
                t[0] = (short)f2bf(v0.x); t[1] = (short)f2bf(v0.y);
                t[2] = (short)f2bf(v0.z); t[3] = (short)f2bf(v0.w);
                t[4] = (short)f2bf(v1.x); t[5] = (short)f2bf(v1.y);
                t[6] = (short)f2bf(v1.z); t[7] = (short)f2bf(v1.w);
                a = t;
            } else {
                a = *(const short8*)&Ab[(size_t)r * NDIM + k];
            }
        }
        #pragma unroll
        for (int n = 0; n < 8; n++) {
            int nn = n * 16 + l15;
            int byte = (nn * 256 + k * 2) ^ ((nn & 7) << 4);
            short8 b = *(const short8*)(sW + byte);
            acc[n] = __builtin_amdgcn_mfma_f32_16x16x32_bf16(a, b, acc[n], 0, 0, 0);
        }
    }

    #pragma unroll
    for (int r = 0; r < 4; r++) {
        int row = rw + lhi * 4 + r;
        float dn = (row < N) ? dinv[row] : 0.f;
        #pragma unroll
        for (int n = 0; n < 8; n++)
            sC[(wave * 16 + lhi * 4 + r) * NDIM + n * 16 + l15] = f2bf(acc[n][r] * dn);
    }
    __syncthreads();
    int row0 = blockIdx.x * 64;
    #pragma unroll
    for (int i = 0; i < 4; i++) {
        int flat = tid + i * 256;
        int row = flat >> 4, c8 = (flat & 15) * 8;
        int gr = row0 + row;
        if (gr < N)
            *(short8*)&C[(size_t)gr * NDIM + c8] = *(const short8*)&sC[row * NDIM + c8];
    }
}

// ---------------- fused aggregate + bias + LN + ReLU (bf16), half-wave/node, MLP-8 ----------------

__global__ __launch_bounds__(256) void k_agg(const ushort* __restrict__ hw, ushort* __restrict__ out,
                                             const float* __restrict__ dinv, const int2* __restrict__ bd,
                                             const ushort* __restrict__ csr,
                                             const float* __restrict__ bias, const float* __restrict__ gamma,
                                             const float* __restrict__ beta, int N) {
    int gtid = blockIdx.x * 256 + threadIdx.x;
    int n = gtid >> 5;
    int l4 = threadIdx.x & 31;
    if (n >= N) return;

    const ushort4* hv = (const ushort4*)hw;
    ushort4 sv = hv[(size_t)n * 32 + l4];
    float a0 = bf2f(sv.x), a1 = bf2f(sv.y), a2 = bf2f(sv.z), a3 = bf2f(sv.w);

    int2 bdv = bd[n];
    int b0 = bdv.x, dg = bdv.y;
    int nfull = dg & ~7;
    ushort4 sa, sb;
    if (nfull > 0) {
        sa = *(const ushort4*)&csr[b0];
        sb = *(const ushort4*)&csr[b0 + 4];
    }
    for (int i = 0; i < nfull; i += 8) {
        ushort4 ca = sa, cb = sb;
        if (i + 8 < nfull) {
            sa = *(const ushort4*)&csr[b0 + i + 8];
            sb = *(const ushort4*)&csr[b0 + i + 12];
        }
        ushort4 t0 = hv[(size_t)ca.x * 32 + l4];
        ushort4 t1 = hv[(size_t)ca.y * 32 + l4];
        ushort4 t2 = hv[(size_t)ca.z * 32 + l4];
        ushort4 t3 = hv[(size_t)ca.w * 32 + l4];
        ushort4 t4 = hv[(size_t)cb.x * 32 + l4];
        ushort4 t5 = hv[(size_t)cb.y * 32 + l4];
        ushort4 t6 = hv[(size_t)cb.z * 32 + l4];
        ushort4 t7 = hv[(size_t)cb.w * 32 + l4];
        a0 += bf2f(t0.x) + bf2f(t1.x) + bf2f(t2.x) + bf2f(t3.x)
            + bf2f(t4.x) + bf2f(t5.x) + bf2f(t6.x) + bf2f(t7.x);
        a1 += bf2f(t0.y) + bf2f(t1.y) + bf2f(t2.y) + bf2f(t3.y)
            + bf2f(t4.y) + bf2f(t5.y) + bf2f(t6.y) + bf2f(t7.y);
        a2 += bf2f(t0.z) + bf2f(t1.z) + bf2f(t2.z) + bf2f(t3.z)
            + bf2f(t4.z) + bf2f(t5.z) + bf2f(t6.z) + bf2f(t7.z);
        a3 += bf2f(t0.w) + bf2f(t1.w) + bf2f(t2.w) + bf2f(t3.w)
            + bf2f(t4.w) + bf2f(t5.w) + bf2f(t6.w) + bf2f(t7.w);
    }
    for (int i = nfull; i < dg; i++) {
        int s = csr[b0 + i];
        ushort4 t = hv[(size_t)s * 32 + l4];
        a0 += bf2f(t.x); a1 += bf2f(t.y); a2 += bf2f(t.z); a3 += bf2f(t.w);
    }

    float dn = dinv[n];
    a0 *= dn; a1 *= dn; a2 *= dn; a3 *= dn;

    float4 bv = ((const float4*)bias)[l4];
    a0 += bv.x; a1 += bv.y; a2 += bv.z; a3 += bv.w;

    float s1 = a0 + a1 + a2 + a3;
    float s2 = a0 * a0 + a1 * a1 + a2 * a2 + a3 * a3;
    #pragma unroll
    for (int o = 1; o < 32; o <<= 1) {
        s1 += __shfl_xor(s1, o);
        s2 += __shfl_xor(s2, o);
    }
    float mu = s1 * (1.f / NDIM);
    float var = s2 * (1.f / NDIM) - mu * mu;
    float rs = rsqrtf(var + LN_EPS);

    float4 gv = ((const float4*)gamma)[l4];
    float4 be = ((const float4*)beta)[l4];
    ushort4 y;
    y.x = f2bf(fmaxf(gv.x * (a0 - mu) * rs + be.x, 0.f));
    y.y = f2bf(fmaxf(gv.y * (a1 - mu) * rs + be.y, 0.f));
    y.z = f2bf(fmaxf(gv.z * (a2 - mu) * rs + be.z, 0.f));
    y.w = f2bf(fmaxf(gv.w * (a3 - mu) * rs + be.w, 0.f));
    ((ushort4*)out)[(size_t)n * 32 + l4] = y;
}

// ---------------- per-graph mean pool ----------------

__global__ __launch_bounds__(256) void k_pool2(const ushort* __restrict__ h, const int* __restrict__ gstart,
                                               const int* __restrict__ gend, float* __restrict__ out) {
    __shared__ float ps[16][128];
    int t = threadIdx.x, g = blockIdx.x;
    int st = gstart[g], en = gend[g];
    int rslot = t >> 4, dc = (t & 15) * 8;
    float acc[8] = {0.f, 0.f, 0.f, 0.f, 0.f, 0.f, 0.f, 0.f};
    for (int r = st + rslot; r < en; r += 16) {
        ushort8 v = *(const ushort8*)&h[(size_t)r * NDIM + dc];
        #pragma unroll
        for (int j = 0; j < 8; j++) acc[j] += bf2f(v[j]);
    }
    #pragma unroll
    for (int j = 0; j < 8; j++) ps[rslot][dc + j] = acc[j];
    __syncthreads();
    if (t < 128) {
        float s = 0.f;
        #pragma unroll
        for (int k = 0; k < 16; k++) s += ps[k][t];
        float c = (float)(en - st);
        out[g * NDIM + t] = s / fmaxf(c, 1.f);
    }
}

// ---------------- launch (9 dispatches) ----------------

extern "C" void kernel_launch(void* const* d_in, const int* in_sizes, int n_in,
                              void* d_out, int out_size, void* d_ws, size_t ws_size,
                              hipStream_t stream) {
    const float* x      = (const float*)d_in[0];
    const int*   ei     = (const int*)d_in[1];
    const int*   batch  = (const int*)d_in[2];
    const float* Ws     = (const float*)d_in[3];
    const float* bs     = (const float*)d_in[4];
    const float* gammas = (const float*)d_in[5];
    const float* betas  = (const float*)d_in[6];
    float* out = (float*)d_out;

    int N = in_sizes[0] / NDIM;
    int E = in_sizes[1] / 2;
    const int* src = ei;
    const int* dst = ei + E;
    int EB = (E + EPB - 1) / EPB;       // 391 (<= 512)
    int NB = (N + 255) / 256;           // 196

    char* w = (char*)d_ws;
    auto alloc = [&](size_t bytes) { char* p = w; w += (bytes + 255) & ~(size_t)255; return p; };
    uint*   hist   = (uint*)alloc((size_t)EB * 257 * 4);
    uint*   arena  = (uint*)alloc((size_t)EB * EPB * 4);
    ushort* csr    = (ushort*)alloc((size_t)NB * CSR_CAP * 2);
    int2*   bd     = (int2*)alloc((size_t)N * 8);
    float*  dinv   = (float*)alloc((size_t)N * 4);
    int*    gse    = (int*)alloc(2 * NGRAPH * 4);
    int*    gstart = gse;
    int*    gend   = gse + NGRAPH;
    ushort* Wt     = (ushort*)alloc((size_t)3 * NDIM * NDIM * 2);
    ushort* bufA   = (ushort*)alloc((size_t)N * NDIM * 2);
    ushort* bufB   = (ushort*)alloc((size_t)N * NDIM * 2);

    k_build1<<<EB, 256, 0, stream>>>(src, dst, hist, arena, E);
    k_sort2b<<<NB + 3, 256, 0, stream>>>(arena, hist, batch, csr, bd, dinv,
                                         gstart, gend, Ws, Wt, N, NB, EB);

    int gGemm = (N + 63) / 64;
    int gAgg  = (N * 32 + 255) / 256;
    for (int l = 0; l < 3; l++) {
        const ushort* wl = Wt + (size_t)l * NDIM * NDIM;
        if (l == 0)
            k_gemm<true><<<gGemm, 256, 0, stream>>>((const void*)x, wl, bufB, dinv, N);
        else
            k_gemm<false><<<gGemm, 256, 0, stream>>>((const void*)bufA, wl, bufB, dinv, N);
        k_agg<<<gAgg, 256, 0, stream>>>(bufB, bufA, dinv, bd, csr,
                                        bs + l * NDIM, gammas + l * NDIM, betas + l * NDIM, N);
    }

    k_pool2<<<NGRAPH, 256, 0, stream>>>(bufA, gstart, gend, out);
}